// Round 5
// baseline (308.900 us; speedup 1.0000x reference)
//
#include <hip/hip_runtime.h>
#include <hip/hip_bf16.h>
#include <hip/hip_fp16.h>

#define T_DIM 2048
#define B_DIM 32
#define LIS_DIM 1024
#define SPE_DIM 1024
#define ATT_DIM 512

typedef _Float16 f16x8 __attribute__((ext_vector_type(8)));
typedef _Float16 f16x4 __attribute__((ext_vector_type(4)));
typedef float f32x4 __attribute__((ext_vector_type(4)));

// K0: pack W into MFMA-fragment order:
// WTf_f16x8[((mat*32+ct)*32+ks)*64 + lane] : h[j] = W[ks*32+hi*8+j][ct*16+lo]
__global__ void transpose_w_kernel(const float* __restrict__ Ws,
                                   const float* __restrict__ Wv,
                                   _Float16* __restrict__ WTf) {
  __shared__ float t17[1024 * 17];
  int blk = blockIdx.x;             // 64 = mat(2) x ct(32)
  int mat = blk >> 5, ct = blk & 31;
  int tid = threadIdx.x;
  const float* W = mat ? Wv : Ws;
  for (int e = tid; e < 16384; e += 256) {
    int k = e >> 4, c = e & 15;
    t17[k * 17 + c] = W[(size_t)k * ATT_DIM + ct * 16 + c];
  }
  __syncthreads();
  int wv4 = tid >> 6, lane = tid & 63, lo = lane & 15, hi = lane >> 4;
  for (int ks = wv4; ks < 32; ks += 4) {
    f16x8 h;
#pragma unroll
    for (int j = 0; j < 8; ++j)
      h[j] = (_Float16)t17[(ks * 32 + hi * 8 + j) * 17 + lo];
    ((f16x8*)WTf)[((size_t)((mat * 32 + ct) * 32 + ks)) * 64 + lane] = h;
  }
}

// K1: q[b][a] = relu(spe[b]·W_proj[:,a] + b_proj[a]), f32
__global__ void query_kernel(const float* __restrict__ spe,
                             const float* __restrict__ Wp,
                             const float* __restrict__ bp,
                             float* __restrict__ q) {
  __shared__ float s[SPE_DIM];
  int b = blockIdx.x;
  for (int i = threadIdx.x; i < SPE_DIM; i += 256) s[i] = spe[(size_t)b * SPE_DIM + i];
  __syncthreads();
  for (int a = threadIdx.x; a < ATT_DIM; a += 256) {
    float acc = bp[a];
    for (int l = 0; l < SPE_DIM; ++l)
      acc = fmaf(s[l], Wp[(size_t)l * ATT_DIM + a], acc);
    q[(size_t)b * ATT_DIM + a] = fmaxf(acc, 0.f);
  }
}

// K2: dual GEMM, M=64 (one b, 64 t's), software-pipelined:
//   - W frags double-buffered in registers (1 kk-step ahead)
//   - x staging split: global->reg issued before chunk's MFMAs, ds_write after
__global__ __launch_bounds__(512, 2)
void dual_gemm_kernel(const float* __restrict__ x,
                      const _Float16* __restrict__ WTf,
                      const float* __restrict__ bs,
                      const float* __restrict__ bv,
                      const float* __restrict__ q,
                      float* __restrict__ scores,
                      _Float16* __restrict__ vals_p) {
  __shared__ __align__(16) char A_lds[2][16384];  // 64 rows x 128k f16, XOR swz
  __shared__ float bk_s[ATT_DIM], bv_s[ATT_DIM], q_s[ATT_DIM];
  __shared__ float red_s[64];

  const int tid = threadIdx.x;
  const int blk = blockIdx.x;
  const int b = blk & 31;
  const int tc = blk >> 5;
  const int t0 = tc * 64;

  bk_s[tid] = bs[tid];
  bv_s[tid] = bv[tid];
  q_s[tid] = q[(size_t)b * ATT_DIM + tid];
  if (tid < 64) red_s[tid] = 0.f;

  const float* xb = x + (size_t)b * LIS_DIM;
  const int wv = tid >> 6;
  const int lane = tid & 63;
  const int lo = lane & 15;
  const int hi = lane >> 4;

  float4 sl[4];  // in-flight stage registers
  auto stage_load = [&](int c) {
    const int k0 = c * 128;
#pragma unroll
    for (int it = 0; it < 4; ++it) {
      int idx = it * 512 + tid;
      int row = idx >> 5;
      int c4 = idx & 31;
      sl[it] = ((const float4*)(xb + (size_t)(t0 + row) * (B_DIM * LIS_DIM) + k0))[c4];
    }
  };
  auto stage_write = [&](int c) {
    char* buf = A_lds[c & 1];
#pragma unroll
    for (int it = 0; it < 4; ++it) {
      int idx = it * 512 + tid;
      int row = idx >> 5;
      int c4 = idx & 31;
      f16x4 h;
      h[0] = (_Float16)sl[it].x; h[1] = (_Float16)sl[it].y;
      h[2] = (_Float16)sl[it].z; h[3] = (_Float16)sl[it].w;
      int off = (row * 256 + c4 * 8) ^ ((row & 7) << 4);
      *(f16x4*)(buf + off) = h;
    }
  };

  f32x4 kacc[4][4], vacc[4][4];
#pragma unroll
  for (int m = 0; m < 4; ++m)
#pragma unroll
    for (int n = 0; n < 4; ++n) {
      kacc[m][n] = (f32x4){0.f, 0.f, 0.f, 0.f};
      vacc[m][n] = (f32x4){0.f, 0.f, 0.f, 0.f};
    }

  stage_load(0);
  stage_write(0);
  __syncthreads();

  const f16x8* Wf = (const f16x8*)WTf;
  f16x8 wkf[2][4], wvf[2][4];  // register double-buffer for W frags
#pragma unroll
  for (int n = 0; n < 4; ++n) {
    wkf[0][n] = Wf[(size_t)((wv * 4 + n) * 32 + 0) * 64 + lane];
    wvf[0][n] = Wf[(size_t)((32 + wv * 4 + n) * 32 + 0) * 64 + lane];
  }

  for (int c = 0; c < 8; ++c) {
    if (c < 7) stage_load(c + 1);
    const char* buf = A_lds[c & 1];
#pragma unroll
    for (int kki = 0; kki < 4; ++kki) {
      const int ks = c * 4 + kki;
      const int kp = (ks + 1 < 32) ? ks + 1 : 31;   // harmless redundant last load
      const int cur = kki & 1, nxt = cur ^ 1;
      // issue next kk-step's W loads (consumed next iteration)
#pragma unroll
      for (int n = 0; n < 4; ++n) {
        wkf[nxt][n] = Wf[(size_t)((wv * 4 + n) * 32 + kp) * 64 + lane];
        wvf[nxt][n] = Wf[(size_t)((32 + wv * 4 + n) * 32 + kp) * 64 + lane];
      }
      // bx reads for current kk-step
      f16x8 bx[4];
#pragma unroll
      for (int m = 0; m < 4; ++m) {
        int row = m * 16 + lo;
        int off = (row * 256 + kki * 64 + hi * 16) ^ ((row & 7) << 4);
        bx[m] = *(const f16x8*)(buf + off);
      }
#pragma unroll
      for (int n = 0; n < 4; ++n)
#pragma unroll
        for (int m = 0; m < 4; ++m) {
          kacc[m][n] = __builtin_amdgcn_mfma_f32_16x16x32_f16(wkf[cur][n], bx[m], kacc[m][n], 0, 0, 0);
          vacc[m][n] = __builtin_amdgcn_mfma_f32_16x16x32_f16(wvf[cur][n], bx[m], vacc[m][n], 0, 0, 0);
        }
    }
    if (c < 7) stage_write(c + 1);
    __syncthreads();
  }

  // vals epilogue: packed lane-natural layout, 512B contiguous per (m,n) store
  _Float16* vp = vals_p + ((size_t)(b * 32 + tc) * 8 + wv) * 4096;
#pragma unroll
  for (int m = 0; m < 4; ++m)
#pragma unroll
    for (int n = 0; n < 4; ++n) {
      int col = wv * 64 + n * 16 + hi * 4;
      f16x4 h;
#pragma unroll
      for (int r = 0; r < 4; ++r)
        h[r] = (_Float16)fmaxf(vacc[m][n][r] + bv_s[col + r], 0.f);
      *(f16x4*)(vp + (m * 4 + n) * 256 + lane * 4) = h;
    }

  // scores epilogue
  float sr[4] = {0.f, 0.f, 0.f, 0.f};
#pragma unroll
  for (int m = 0; m < 4; ++m)
#pragma unroll
    for (int n = 0; n < 4; ++n) {
      int col = wv * 64 + n * 16 + hi * 4;
#pragma unroll
      for (int r = 0; r < 4; ++r)
        sr[m] += q_s[col + r] * fmaxf(kacc[m][n][r] + bk_s[col + r], 0.f);
    }
#pragma unroll
  for (int m = 0; m < 4; ++m) {
    sr[m] += __shfl_xor(sr[m], 16, 64);
    sr[m] += __shfl_xor(sr[m], 32, 64);
    if (lane < 16) atomicAdd(&red_s[m * 16 + lo], sr[m]);
  }
  __syncthreads();
  if (tid < 64) scores[(size_t)b * T_DIM + t0 + tid] = red_s[tid];
}

// K3: masked softmax per b; writes attn f32 to out, zeroes context region of out
__global__ void softmax_kernel(const float* __restrict__ scores,
                               const int* __restrict__ llen,
                               float* __restrict__ attn_out,   // d_out + 16384
                               float* __restrict__ ctx_out) {  // d_out (zeroed here)
  __shared__ float rmax[4], rsum[4];
  int b = blockIdx.x, tid = threadIdx.x;
  int L = llen[b];
  float v[8];
  float mx = -1e30f;
  for (int i = 0; i < 8; ++i) {
    int t = i * 256 + tid;
    float s = scores[(size_t)b * T_DIM + t];
    if (t >= L) s -= 100.f;
    v[i] = s;
    mx = fmaxf(mx, s);
  }
  for (int d = 1; d < 64; d <<= 1) mx = fmaxf(mx, __shfl_xor(mx, d, 64));
  if ((tid & 63) == 0) rmax[tid >> 6] = mx;
  __syncthreads();
  mx = fmaxf(fmaxf(rmax[0], rmax[1]), fmaxf(rmax[2], rmax[3]));
  float sum = 0.f;
  for (int i = 0; i < 8; ++i) { v[i] = expf(v[i] - mx); sum += v[i]; }
  for (int d = 1; d < 64; d <<= 1) sum += __shfl_xor(sum, d, 64);
  if ((tid & 63) == 0) rsum[tid >> 6] = sum;
  __syncthreads();
  sum = rsum[0] + rsum[1] + rsum[2] + rsum[3];
  float inv = 1.f / sum;
  for (int i = 0; i < 8; ++i) {
    int t = i * 256 + tid;
    attn_out[(size_t)b * T_DIM + t] = v[i] * inv;
  }
  for (int i = tid; i < ATT_DIM; i += 256) ctx_out[(size_t)b * ATT_DIM + i] = 0.f;
}

// K4: ctx[b][col] = sum_t attn[b][t] * vals[t][col], decoding packed layout.
__global__ __launch_bounds__(512)
void ctx_kernel(const _Float16* __restrict__ vals_p,
                const float* __restrict__ attn,
                float* __restrict__ ctx) {
  __shared__ float attn_s[512];
  int blk = blockIdx.x;
  int b = blk >> 2, tcg = blk & 3;
  int tid = threadIdx.x;
  int wv = tid >> 6, lane = tid & 63, lo = lane & 15, hi = lane >> 4;
  attn_s[tid] = attn[(size_t)b * T_DIM + tcg * 512 + tid];
  __syncthreads();
  float cacc[4][4] = {};
  for (int i = 0; i < 8; ++i) {
    int tc = tcg * 8 + i;
    const _Float16* vp = vals_p + ((size_t)(b * 32 + tc) * 8 + wv) * 4096;
#pragma unroll
    for (int m = 0; m < 4; ++m) {
      float w = attn_s[i * 64 + m * 16 + lo];
#pragma unroll
      for (int n = 0; n < 4; ++n) {
        f16x4 v = *(const f16x4*)(vp + (m * 4 + n) * 256 + lane * 4);
#pragma unroll
        for (int r = 0; r < 4; ++r) cacc[n][r] += w * (float)v[r];
      }
    }
  }
#pragma unroll
  for (int n = 0; n < 4; ++n)
#pragma unroll
    for (int r = 0; r < 4; ++r) {
      float v = cacc[n][r];
      v += __shfl_xor(v, 1, 64);
      v += __shfl_xor(v, 2, 64);
      v += __shfl_xor(v, 4, 64);
      v += __shfl_xor(v, 8, 64);
      if (lo == 0)
        atomicAdd(&ctx[(size_t)b * ATT_DIM + wv * 64 + n * 16 + hi * 4 + r], v);
    }
}

extern "C" void kernel_launch(void* const* d_in, const int* in_sizes, int n_in,
                              void* d_out, int out_size, void* d_ws, size_t ws_size,
                              hipStream_t stream) {
  const float* x   = (const float*)d_in[0];
  const float* spe = (const float*)d_in[1];
  const int*   len = (const int*)d_in[2];
  const float* Ws  = (const float*)d_in[4];
  const float* bs  = (const float*)d_in[5];
  const float* Wv  = (const float*)d_in[6];
  const float* bv  = (const float*)d_in[7];
  const float* Wp  = (const float*)d_in[8];
  const float* bp  = (const float*)d_in[9];
  float* out = (float*)d_out;  // [0,16384): context f32, [16384,81920): attn f32

  char* ws = (char*)d_ws;
  _Float16* WTf  = (_Float16*)ws;                            // 2 MB packed frags
  float* q       = (float*)(ws + (2u << 20));                // 64 KB
  float* scores  = (float*)(ws + (2u << 20) + (64u << 10));  // 256 KB
  _Float16* vals = (_Float16*)(ws + (4u << 20));             // 64 MB packed

  transpose_w_kernel<<<dim3(64), dim3(256), 0, stream>>>(Ws, Wv, WTf);
  query_kernel<<<dim3(32), dim3(256), 0, stream>>>(spe, Wp, bp, q);
  dual_gemm_kernel<<<dim3(1024), dim3(512), 0, stream>>>(x, WTf, bs, bv, q, scores, vals);
  softmax_kernel<<<dim3(32), dim3(256), 0, stream>>>(scores, len, out + 16384, out);
  ctx_kernel<<<dim3(128), dim3(512), 0, stream>>>(vals, out + 16384, out);
}

// Round 7
// 253.913 us; speedup vs baseline: 1.2166x; 1.2166x over previous
//
#include <hip/hip_runtime.h>
#include <hip/hip_bf16.h>
#include <hip/hip_fp16.h>

#define T_DIM 2048
#define B_DIM 32
#define LIS_DIM 1024
#define SPE_DIM 1024
#define ATT_DIM 512

typedef _Float16 f16x8 __attribute__((ext_vector_type(8)));
typedef _Float16 f16x4 __attribute__((ext_vector_type(4)));
typedef float f32x4 __attribute__((ext_vector_type(4)));

// K0: pack W into MFMA-fragment order:
// WTf_f16x8[((mat*32+ct)*32+ks)*64 + lane] : h[j] = W[ks*32+hi*8+j][ct*16+lo]
__global__ void transpose_w_kernel(const float* __restrict__ Ws,
                                   const float* __restrict__ Wv,
                                   _Float16* __restrict__ WTf) {
  __shared__ float t17[1024 * 17];
  int blk = blockIdx.x;             // 64 = mat(2) x ct(32)
  int mat = blk >> 5, ct = blk & 31;
  int tid = threadIdx.x;
  const float* W = mat ? Wv : Ws;
  for (int e = tid; e < 16384; e += 256) {
    int k = e >> 4, c = e & 15;
    t17[k * 17 + c] = W[(size_t)k * ATT_DIM + ct * 16 + c];
  }
  __syncthreads();
  int wv4 = tid >> 6, lane = tid & 63, lo = lane & 15, hi = lane >> 4;
  for (int ks = wv4; ks < 32; ks += 4) {
    f16x8 h;
#pragma unroll
    for (int j = 0; j < 8; ++j)
      h[j] = (_Float16)t17[(ks * 32 + hi * 8 + j) * 17 + lo];
    ((f16x8*)WTf)[((size_t)((mat * 32 + ct) * 32 + ks)) * 64 + lane] = h;
  }
}

// K1: q[b][a] = relu(spe[b]·W_proj[:,a] + b_proj[a]), f32
__global__ void query_kernel(const float* __restrict__ spe,
                             const float* __restrict__ Wp,
                             const float* __restrict__ bp,
                             float* __restrict__ q) {
  __shared__ float s[SPE_DIM];
  int b = blockIdx.x;
  for (int i = threadIdx.x; i < SPE_DIM; i += 256) s[i] = spe[(size_t)b * SPE_DIM + i];
  __syncthreads();
  for (int a = threadIdx.x; a < ATT_DIM; a += 256) {
    float acc = bp[a];
    for (int l = 0; l < SPE_DIM; ++l)
      acc = fmaf(s[l], Wp[(size_t)l * ATT_DIM + a], acc);
    q[(size_t)b * ATT_DIM + a] = fmaxf(acc, 0.f);
  }
}

// K2: dual GEMM, M=64 (one b, 64 t's).
// x staged via NON-TEMPORAL loads (don't pollute L2 -> W frags stay L2-resident).
// vals written via non-temporal stores.
__global__ __launch_bounds__(512, 2)
void dual_gemm_kernel(const float* __restrict__ x,
                      const _Float16* __restrict__ WTf,
                      const float* __restrict__ bs,
                      const float* __restrict__ bv,
                      const float* __restrict__ q,
                      float* __restrict__ scores,
                      _Float16* __restrict__ vals_p) {
  __shared__ __align__(16) char A_lds[2][16384];  // 64 rows x 128k f16, XOR swz
  __shared__ float bk_s[ATT_DIM], bv_s[ATT_DIM], q_s[ATT_DIM];
  __shared__ float red_s[64];

  const int tid = threadIdx.x;
  const int blk = blockIdx.x;
  const int b = blk & 31;
  const int tc = blk >> 5;
  const int t0 = tc * 64;

  bk_s[tid] = bs[tid];
  bv_s[tid] = bv[tid];
  q_s[tid] = q[(size_t)b * ATT_DIM + tid];
  if (tid < 64) red_s[tid] = 0.f;

  const float* xb = x + (size_t)b * LIS_DIM;
  const int wv = tid >> 6;
  const int lane = tid & 63;
  const int lo = lane & 15;
  const int hi = lane >> 4;

  f32x4 sl[4];  // in-flight stage registers
  auto stage_load = [&](int c) {
    const int k0 = c * 128;
#pragma unroll
    for (int it = 0; it < 4; ++it) {
      int idx = it * 512 + tid;
      int row = idx >> 5;
      int c4 = idx & 31;
      sl[it] = __builtin_nontemporal_load(
          (const f32x4*)(xb + (size_t)(t0 + row) * (B_DIM * LIS_DIM) + k0) + c4);
    }
  };
  auto stage_write = [&](int c) {
    char* buf = A_lds[c & 1];
#pragma unroll
    for (int it = 0; it < 4; ++it) {
      int idx = it * 512 + tid;
      int row = idx >> 5;
      int c4 = idx & 31;
      f16x4 h;
      h[0] = (_Float16)sl[it][0]; h[1] = (_Float16)sl[it][1];
      h[2] = (_Float16)sl[it][2]; h[3] = (_Float16)sl[it][3];
      int off = (row * 256 + c4 * 8) ^ ((row & 7) << 4);
      *(f16x4*)(buf + off) = h;
    }
  };

  f32x4 kacc[4][4], vacc[4][4];
#pragma unroll
  for (int m = 0; m < 4; ++m)
#pragma unroll
    for (int n = 0; n < 4; ++n) {
      kacc[m][n] = (f32x4){0.f, 0.f, 0.f, 0.f};
      vacc[m][n] = (f32x4){0.f, 0.f, 0.f, 0.f};
    }

  stage_load(0);
  stage_write(0);
  __syncthreads();

  const f16x8* Wf = (const f16x8*)WTf;
  f16x8 wkf[2][4], wvf[2][4];  // register double-buffer for W frags
#pragma unroll
  for (int n = 0; n < 4; ++n) {
    wkf[0][n] = Wf[(size_t)((wv * 4 + n) * 32 + 0) * 64 + lane];
    wvf[0][n] = Wf[(size_t)((32 + wv * 4 + n) * 32 + 0) * 64 + lane];
  }

  for (int c = 0; c < 8; ++c) {
    if (c < 7) stage_load(c + 1);
    const char* buf = A_lds[c & 1];
#pragma unroll
    for (int kki = 0; kki < 4; ++kki) {
      const int ks = c * 4 + kki;
      const int kp = (ks + 1 < 32) ? ks + 1 : 31;
      const int cur = kki & 1, nxt = cur ^ 1;
#pragma unroll
      for (int n = 0; n < 4; ++n) {
        wkf[nxt][n] = Wf[(size_t)((wv * 4 + n) * 32 + kp) * 64 + lane];
        wvf[nxt][n] = Wf[(size_t)((32 + wv * 4 + n) * 32 + kp) * 64 + lane];
      }
      f16x8 bx[4];
#pragma unroll
      for (int m = 0; m < 4; ++m) {
        int row = m * 16 + lo;
        int off = (row * 256 + kki * 64 + hi * 16) ^ ((row & 7) << 4);
        bx[m] = *(const f16x8*)(buf + off);
      }
#pragma unroll
      for (int n = 0; n < 4; ++n)
#pragma unroll
        for (int m = 0; m < 4; ++m) {
          kacc[m][n] = __builtin_amdgcn_mfma_f32_16x16x32_f16(wkf[cur][n], bx[m], kacc[m][n], 0, 0, 0);
          vacc[m][n] = __builtin_amdgcn_mfma_f32_16x16x32_f16(wvf[cur][n], bx[m], vacc[m][n], 0, 0, 0);
        }
    }
    if (c < 7) stage_write(c + 1);
    __syncthreads();
  }

  // vals epilogue: packed lane-natural layout, non-temporal 8B stores
  _Float16* vp = vals_p + ((size_t)(b * 32 + tc) * 8 + wv) * 4096;
#pragma unroll
  for (int m = 0; m < 4; ++m)
#pragma unroll
    for (int n = 0; n < 4; ++n) {
      int col = wv * 64 + n * 16 + hi * 4;
      f16x4 h;
#pragma unroll
      for (int r = 0; r < 4; ++r)
        h[r] = (_Float16)fmaxf(vacc[m][n][r] + bv_s[col + r], 0.f);
      __builtin_nontemporal_store(h, (f16x4*)(vp + (m * 4 + n) * 256 + lane * 4));
    }

  // scores epilogue
  float sr[4] = {0.f, 0.f, 0.f, 0.f};
#pragma unroll
  for (int m = 0; m < 4; ++m)
#pragma unroll
    for (int n = 0; n < 4; ++n) {
      int col = wv * 64 + n * 16 + hi * 4;
#pragma unroll
      for (int r = 0; r < 4; ++r)
        sr[m] += q_s[col + r] * fmaxf(kacc[m][n][r] + bk_s[col + r], 0.f);
    }
#pragma unroll
  for (int m = 0; m < 4; ++m) {
    sr[m] += __shfl_xor(sr[m], 16, 64);
    sr[m] += __shfl_xor(sr[m], 32, 64);
    if (lane < 16) atomicAdd(&red_s[m * 16 + lo], sr[m]);
  }
  __syncthreads();
  if (tid < 64) scores[(size_t)b * T_DIM + t0 + tid] = red_s[tid];
}

// K3: masked softmax per b; writes attn f32 to out, zeroes context region of out
__global__ void softmax_kernel(const float* __restrict__ scores,
                               const int* __restrict__ llen,
                               float* __restrict__ attn_out,   // d_out + 16384
                               float* __restrict__ ctx_out) {  // d_out (zeroed here)
  __shared__ float rmax[4], rsum[4];
  int b = blockIdx.x, tid = threadIdx.x;
  int L = llen[b];
  float v[8];
  float mx = -1e30f;
  for (int i = 0; i < 8; ++i) {
    int t = i * 256 + tid;
    float s = scores[(size_t)b * T_DIM + t];
    if (t >= L) s -= 100.f;
    v[i] = s;
    mx = fmaxf(mx, s);
  }
  for (int d = 1; d < 64; d <<= 1) mx = fmaxf(mx, __shfl_xor(mx, d, 64));
  if ((tid & 63) == 0) rmax[tid >> 6] = mx;
  __syncthreads();
  mx = fmaxf(fmaxf(rmax[0], rmax[1]), fmaxf(rmax[2], rmax[3]));
  float sum = 0.f;
  for (int i = 0; i < 8; ++i) { v[i] = expf(v[i] - mx); sum += v[i]; }
  for (int d = 1; d < 64; d <<= 1) sum += __shfl_xor(sum, d, 64);
  if ((tid & 63) == 0) rsum[tid >> 6] = sum;
  __syncthreads();
  sum = rsum[0] + rsum[1] + rsum[2] + rsum[3];
  float inv = 1.f / sum;
  for (int i = 0; i < 8; ++i) {
    int t = i * 256 + tid;
    attn_out[(size_t)b * T_DIM + t] = v[i] * inv;
  }
  for (int i = tid; i < ATT_DIM; i += 256) ctx_out[(size_t)b * ATT_DIM + i] = 0.f;
}

// K4: ctx[b][col] = sum_t attn[b][t] * vals[t][col], decoding packed layout.
// grid 256 = b(32) x tcg(8); each block does 4 tc-chunks (256 t).
__global__ __launch_bounds__(512)
void ctx_kernel(const _Float16* __restrict__ vals_p,
                const float* __restrict__ attn,
                float* __restrict__ ctx) {
  __shared__ float attn_s[256];
  int blk = blockIdx.x;
  int b = blk >> 3, tcg = blk & 7;
  int tid = threadIdx.x;
  int wv = tid >> 6, lane = tid & 63, lo = lane & 15, hi = lane >> 4;
  if (tid < 256) attn_s[tid] = attn[(size_t)b * T_DIM + tcg * 256 + tid];
  __syncthreads();
  float cacc[4][4] = {};
  for (int i = 0; i < 4; ++i) {
    int tc = tcg * 4 + i;
    const _Float16* vp = vals_p + ((size_t)(b * 32 + tc) * 8 + wv) * 4096;
#pragma unroll
    for (int m = 0; m < 4; ++m) {
      float w = attn_s[i * 64 + m * 16 + lo];
#pragma unroll
      for (int n = 0; n < 4; ++n) {
        f16x4 v = __builtin_nontemporal_load(
            (const f16x4*)(vp + (m * 4 + n) * 256 + lane * 4));
#pragma unroll
        for (int r = 0; r < 4; ++r) cacc[n][r] += w * (float)v[r];
      }
    }
  }
#pragma unroll
  for (int n = 0; n < 4; ++n)
#pragma unroll
    for (int r = 0; r < 4; ++r) {
      float v = cacc[n][r];
      v += __shfl_xor(v, 1, 64);
      v += __shfl_xor(v, 2, 64);
      v += __shfl_xor(v, 4, 64);
      v += __shfl_xor(v, 8, 64);
      if (lo == 0)
        atomicAdd(&ctx[(size_t)b * ATT_DIM + wv * 64 + n * 16 + hi * 4 + r], v);
    }
}

extern "C" void kernel_launch(void* const* d_in, const int* in_sizes, int n_in,
                              void* d_out, int out_size, void* d_ws, size_t ws_size,
                              hipStream_t stream) {
  const float* x   = (const float*)d_in[0];
  const float* spe = (const float*)d_in[1];
  const int*   len = (const int*)d_in[2];
  const float* Ws  = (const float*)d_in[4];
  const float* bs  = (const float*)d_in[5];
  const float* Wv  = (const float*)d_in[6];
  const float* bv  = (const float*)d_in[7];
  const float* Wp  = (const float*)d_in[8];
  const float* bp  = (const float*)d_in[9];
  float* out = (float*)d_out;  // [0,16384): context f32, [16384,81920): attn f32

  char* ws = (char*)d_ws;
  _Float16* WTf  = (_Float16*)ws;                            // 2 MB packed frags
  float* q       = (float*)(ws + (2u << 20));                // 64 KB
  float* scores  = (float*)(ws + (2u << 20) + (64u << 10));  // 256 KB
  _Float16* vals = (_Float16*)(ws + (4u << 20));             // 64 MB packed

  transpose_w_kernel<<<dim3(64), dim3(256), 0, stream>>>(Ws, Wv, WTf);
  query_kernel<<<dim3(32), dim3(256), 0, stream>>>(spe, Wp, bp, q);
  dual_gemm_kernel<<<dim3(1024), dim3(512), 0, stream>>>(x, WTf, bs, bv, q, scores, vals);
  softmax_kernel<<<dim3(32), dim3(256), 0, stream>>>(scores, len, out + 16384, out);
  ctx_kernel<<<dim3(256), dim3(512), 0, stream>>>(vals, out + 16384, out);
}